// Round 20
// baseline (359.840 us; speedup 1.0000x reference)
//
#include <hip/hip_runtime.h>

#define NHEADS 12
#define HDIM 128
#define MODEL_DIM 1536
#define MAX_ATTN_W 13200
#define NSPLIT 18

typedef unsigned short u16;
typedef unsigned int u32;
typedef float f32x4 __attribute__((ext_vector_type(4)));
typedef float f32x16 __attribute__((ext_vector_type(16)));
typedef __bf16 bf16x8 __attribute__((ext_vector_type(8)));

static __device__ __forceinline__ u16 f2bf(float f) {
  union { __bf16 h; u16 u; } cv;
  cv.h = (__bf16)f;
  return cv.u;
}
static __device__ __forceinline__ float bf2f(u16 u) {
  union { u32 u; float f; } cv;
  cv.u = ((u32)u) << 16;
  return cv.f;
}
static __device__ __forceinline__ u32 pk2(float a, float b) {
  return (u32)f2bf(a) | ((u32)f2bf(b) << 16);
}
// async global->LDS, 16B per lane; LDS dest = wave-uniform base + lane*16
static __device__ __forceinline__ void gload_lds16(const void* g, void* l) {
  __builtin_amdgcn_global_load_lds(
      (const __attribute__((address_space(1))) unsigned int*)g,
      (__attribute__((address_space(3))) unsigned int*)l, 16, 0, 0);
}

// ---------------- fused prep: converts + K-window + V^T-window in ONE launch ----------------
__launch_bounds__(256)
__global__ void k_prep(const float* __restrict__ x, int nx4,
                       const float* __restrict__ wq, const float* __restrict__ wk,
                       const float* __restrict__ wv, const float* __restrict__ wo, int nw4,
                       u16* __restrict__ xb, u16* __restrict__ wqb, u16* __restrict__ wkb,
                       u16* __restrict__ wvb, u16* __restrict__ wob,
                       const float* __restrict__ kc, const float* __restrict__ vc,
                       u16* __restrict__ K_all, u16* __restrict__ VT,
                       const int* __restrict__ csp, int S, int KVcap) {
  const int tid = threadIdx.x;
  const int which = blockIdx.y;

  if (which <= 4) {
    const float* src = (which == 0) ? x : (which == 1) ? wq : (which == 2) ? wk
                       : (which == 3) ? wv : wo;
    u16* dst = (which == 0) ? xb : (which == 1) ? wqb : (which == 2) ? wkb
               : (which == 3) ? wvb : wob;
    const int n4 = (which == 0) ? nx4 : nw4;
    for (int i = blockIdx.x * 256 + tid; i < n4; i += gridDim.x * 256) {
      float4 v = ((const float4*)src)[i];
      ((uint2*)dst)[i] = make_uint2(pk2(v.x, v.y), pk2(v.z, v.w));
    }
    return;
  }

  const int cs = csp[0];
  const int ce = cs + S;
  int wst = ce - MAX_ATTN_W; if (wst < 0) wst = 0;
  const int oldlen = cs - wst;

  if (which == 5) {
    const long per = (long)oldlen * 16;   // 16 chunks of 8 along d
    const long total = per * NHEADS;
    for (long c = blockIdx.x * 256L + tid; c < total; c += (long)gridDim.x * 256) {
      int n = (int)(c / per);
      long r = c - (long)n * per;
      int jo = (int)(r >> 4);
      int dc = ((int)r & 15) * 8;
      const float* s = kc + ((size_t)(wst + jo) * NHEADS + n) * HDIM + dc;
      float4 a = *(const float4*)s;
      float4 b = *(const float4*)(s + 4);
      uint4 o;
      o.x = pk2(a.x, a.y);
      o.y = pk2(a.z, a.w);
      o.z = pk2(b.x, b.y);
      o.w = pk2(b.z, b.w);
      *(uint4*)(K_all + ((size_t)n * KVcap + jo) * HDIM + dc) = o;
    }
    return;
  }

  // which == 6: V^T window [n][d][jj] via LDS tile transpose (64 j x 128 d per block)
  __shared__ u16 tile[64][130];
  const int njb = (KVcap + 63) >> 6;
  const int bx = blockIdx.x;
  if (bx >= njb * NHEADS) return;
  const int n = bx / njb;
  const int j0 = (bx - n * njb) * 64;
  if (j0 >= oldlen) return;

  #pragma unroll
  for (int i = 0; i < 8; i++) {
    int idx = tid + 256 * i;
    int jr = idx >> 5;
    int dc = (idx & 31) * 4;
    float4 v = make_float4(0.f, 0.f, 0.f, 0.f);
    if (j0 + jr < oldlen)
      v = *(const float4*)(vc + ((size_t)(wst + j0 + jr) * NHEADS + n) * HDIM + dc);
    *(u32*)&tile[jr][dc] = pk2(v.x, v.y);
    *(u32*)&tile[jr][dc + 2] = pk2(v.z, v.w);
  }
  __syncthreads();

  const int d = tid >> 1;
  const int jh = (tid & 1) * 32;
  alignas(16) u16 buf[32];
  #pragma unroll
  for (int jr = 0; jr < 32; jr++) buf[jr] = tile[jh + jr][d];
  u16* dst = VT + ((size_t)n * HDIM + d) * KVcap + j0 + jh;
  if (j0 + jh + 32 <= oldlen) {
    #pragma unroll
    for (int c = 0; c < 4; c++)
      *(uint4*)(dst + c * 8) = *(const uint4*)&buf[c * 8];
  } else {
    for (int jr = 0; jr < 32 && j0 + jh + jr < oldlen; jr++) dst[jr] = buf[jr];
  }
}

// ---------------- out-proj GEMM, 128x128 tile, counted-vmcnt dbuf (1 barrier/K-step) ----------------
__launch_bounds__(256)
__global__ void k_gemm_o128(const u16* __restrict__ A, const u16* __restrict__ B,
                            const float* __restrict__ bias, float* __restrict__ out,
                            int M, int N, int K) {
  __shared__ __align__(16) u16 Al[2][128][40];
  __shared__ __align__(16) u16 Bl[2][128][40];
  const int n0 = blockIdx.y * 128;
  const int tid = threadIdx.x;
  const int wid = tid >> 6, l = tid & 63, l31 = l & 31, hi = l >> 5;
  const int wr = wid >> 1, wc = wid & 1;
  const int m0 = blockIdx.x * 128;
  f32x16 acc[2][2];
  #pragma unroll
  for (int mt = 0; mt < 2; mt++)
    #pragma unroll
    for (int nt = 0; nt < 2; nt++)
      #pragma unroll
      for (int j = 0; j < 16; j++) acc[mt][nt][j] = 0.f;
  const int row = tid >> 2, colc = (tid & 3) * 8;
  const u16* Ar0 = A + (size_t)(m0 + row) * K + colc;
  const u16* Ar1 = A + (size_t)(m0 + row + 64) * K + colc;
  const u16* Br0 = B + (size_t)(n0 + row) * K + colc;
  const u16* Br1 = B + (size_t)(n0 + row + 64) * K + colc;

  uint4 ra0, ra1, ra2, ra3, rb0, rb1, rb2, rb3;
  auto loadA = [&](int k0) {
    ra0 = *(const uint4*)(Ar0 + k0); ra1 = *(const uint4*)(Ar1 + k0);
    ra2 = *(const uint4*)(Br0 + k0); ra3 = *(const uint4*)(Br1 + k0);
  };
  auto loadB = [&](int k0) {
    rb0 = *(const uint4*)(Ar0 + k0); rb1 = *(const uint4*)(Ar1 + k0);
    rb2 = *(const uint4*)(Br0 + k0); rb3 = *(const uint4*)(Br1 + k0);
  };
  auto mfma_step = [&](int p) {
    #pragma unroll
    for (int ks = 0; ks < 2; ks++) {
      bf16x8 af[2], bfr[2];
      #pragma unroll
      for (int mt = 0; mt < 2; mt++)
        af[mt] = *(const bf16x8*)&Al[p][wr * 64 + mt * 32 + l31][ks * 16 + hi * 8];
      #pragma unroll
      for (int nt = 0; nt < 2; nt++)
        bfr[nt] = *(const bf16x8*)&Bl[p][wc * 64 + nt * 32 + l31][ks * 16 + hi * 8];
      #pragma unroll
      for (int mt = 0; mt < 2; mt++)
        #pragma unroll
        for (int nt = 0; nt < 2; nt++)
          acc[mt][nt] = __builtin_amdgcn_mfma_f32_32x32x16_bf16(af[mt], bfr[nt], acc[mt][nt], 0, 0, 0);
    }
  };

  const int nk = K / 32;   // even
  loadA(0);
  for (int t = 0; t < nk; t += 2) {
    const int k0 = t * 32;
    if (t + 1 < nk) loadB(k0 + 32);
    __builtin_amdgcn_sched_barrier(0);
    if (t + 1 < nk) asm volatile("s_waitcnt vmcnt(4)" ::: "memory");
    else            asm volatile("s_waitcnt vmcnt(0)" ::: "memory");
    __builtin_amdgcn_sched_barrier(0);
    *(uint4*)&Al[0][row][colc] = ra0;
    *(uint4*)&Al[0][row + 64][colc] = ra1;
    *(uint4*)&Bl[0][row][colc] = ra2;
    *(uint4*)&Bl[0][row + 64][colc] = ra3;
    asm volatile("s_waitcnt lgkmcnt(0)" ::: "memory");
    __builtin_amdgcn_s_barrier();
    __builtin_amdgcn_sched_barrier(0);
    mfma_step(0);
    if (t + 2 < nk) loadA(k0 + 64);
    __builtin_amdgcn_sched_barrier(0);
    if (t + 2 < nk) asm volatile("s_waitcnt vmcnt(4)" ::: "memory");
    else            asm volatile("s_waitcnt vmcnt(0)" ::: "memory");
    __builtin_amdgcn_sched_barrier(0);
    *(uint4*)&Al[1][row][colc] = rb0;
    *(uint4*)&Al[1][row + 64][colc] = rb1;
    *(uint4*)&Bl[1][row][colc] = rb2;
    *(uint4*)&Bl[1][row + 64][colc] = rb3;
    asm volatile("s_waitcnt lgkmcnt(0)" ::: "memory");
    __builtin_amdgcn_s_barrier();
    __builtin_amdgcn_sched_barrier(0);
    mfma_step(1);
  }
  #pragma unroll
  for (int mt = 0; mt < 2; mt++)
    #pragma unroll
    for (int nt = 0; nt < 2; nt++) {
      const int col = n0 + wc * 64 + nt * 32 + l31;
      const float bb = bias[col];
      #pragma unroll
      for (int r = 0; r < 16; r++) {
        int rowo = m0 + wr * 64 + mt * 32 + (r & 3) + 8 * (r >> 2) + 4 * hi;
        if (rowo < M) out[(size_t)rowo * N + col] = acc[mt][nt][r] + bb;
      }
    }
}

// ---------------- fused QKV GEMM, 128x128 tile, counted-vmcnt dbuf (1 barrier/K-step) ----------------
__launch_bounds__(256)
__global__ void k_gemm_qkv128(const u16* __restrict__ A,
                              const u16* __restrict__ B0, const u16* __restrict__ B1,
                              const u16* __restrict__ B2,
                              const float* __restrict__ bias0, const float* __restrict__ bias1,
                              const float* __restrict__ bias2,
                              float* __restrict__ o0, float* __restrict__ o1, float* __restrict__ o2,
                              int M, int N, int K) {
  __shared__ __align__(16) u16 Al[2][128][40];
  __shared__ __align__(16) u16 Bl[2][128][40];
  const int nblk = N / 128;
  const int which = blockIdx.y / nblk;
  const int n0 = (blockIdx.y % nblk) * 128;
  const u16* B = (which == 0) ? B0 : ((which == 1) ? B1 : B2);
  const float* bias = (which == 0) ? bias0 : ((which == 1) ? bias1 : bias2);
  float* out = (which == 0) ? o0 : ((which == 1) ? o1 : o2);
  const int tid = threadIdx.x;
  const int wid = tid >> 6, l = tid & 63, l31 = l & 31, hi = l >> 5;
  const int wr = wid >> 1, wc = wid & 1;
  const int m0 = blockIdx.x * 128;
  f32x16 acc[2][2];
  #pragma unroll
  for (int mt = 0; mt < 2; mt++)
    #pragma unroll
    for (int nt = 0; nt < 2; nt++)
      #pragma unroll
      for (int j = 0; j < 16; j++) acc[mt][nt][j] = 0.f;
  const int row = tid >> 2, colc = (tid & 3) * 8;
  const u16* Ar0 = A + (size_t)(m0 + row) * K + colc;
  const u16* Ar1 = A + (size_t)(m0 + row + 64) * K + colc;
  const u16* Br0 = B + (size_t)(n0 + row) * K + colc;
  const u16* Br1 = B + (size_t)(n0 + row + 64) * K + colc;

  uint4 ra0, ra1, ra2, ra3, rb0, rb1, rb2, rb3;
  auto loadA = [&](int k0) {
    ra0 = *(const uint4*)(Ar0 + k0); ra1 = *(const uint4*)(Ar1 + k0);
    ra2 = *(const uint4*)(Br0 + k0); ra3 = *(const uint4*)(Br1 + k0);
  };
  auto loadB = [&](int k0) {
    rb0 = *(const uint4*)(Ar0 + k0); rb1 = *(const uint4*)(Ar1 + k0);
    rb2 = *(const uint4*)(Br0 + k0); rb3 = *(const uint4*)(Br1 + k0);
  };
  auto mfma_step = [&](int p) {
    #pragma unroll
    for (int ks = 0; ks < 2; ks++) {
      bf16x8 af[2], bfr[2];
      #pragma unroll
      for (int mt = 0; mt < 2; mt++)
        af[mt] = *(const bf16x8*)&Al[p][wr * 64 + mt * 32 + l31][ks * 16 + hi * 8];
      #pragma unroll
      for (int nt = 0; nt < 2; nt++)
        bfr[nt] = *(const bf16x8*)&Bl[p][wc * 64 + nt * 32 + l31][ks * 16 + hi * 8];
      #pragma unroll
      for (int mt = 0; mt < 2; mt++)
        #pragma unroll
        for (int nt = 0; nt < 2; nt++)
          acc[mt][nt] = __builtin_amdgcn_mfma_f32_32x32x16_bf16(af[mt], bfr[nt], acc[mt][nt], 0, 0, 0);
    }
  };

  const int nk = K / 32;   // even
  loadA(0);
  for (int t = 0; t < nk; t += 2) {
    const int k0 = t * 32;
    if (t + 1 < nk) loadB(k0 + 32);
    __builtin_amdgcn_sched_barrier(0);
    if (t + 1 < nk) asm volatile("s_waitcnt vmcnt(4)" ::: "memory");
    else            asm volatile("s_waitcnt vmcnt(0)" ::: "memory");
    __builtin_amdgcn_sched_barrier(0);
    *(uint4*)&Al[0][row][colc] = ra0;
    *(uint4*)&Al[0][row + 64][colc] = ra1;
    *(uint4*)&Bl[0][row][colc] = ra2;
    *(uint4*)&Bl[0][row + 64][colc] = ra3;
    asm volatile("s_waitcnt lgkmcnt(0)" ::: "memory");
    __builtin_amdgcn_s_barrier();
    __builtin_amdgcn_sched_barrier(0);
    mfma_step(0);
    if (t + 2 < nk) loadA(k0 + 64);
    __builtin_amdgcn_sched_barrier(0);
    if (t + 2 < nk) asm volatile("s_waitcnt vmcnt(4)" ::: "memory");
    else            asm volatile("s_waitcnt vmcnt(0)" ::: "memory");
    __builtin_amdgcn_sched_barrier(0);
    *(uint4*)&Al[1][row][colc] = rb0;
    *(uint4*)&Al[1][row + 64][colc] = rb1;
    *(uint4*)&Bl[1][row][colc] = rb2;
    *(uint4*)&Bl[1][row + 64][colc] = rb3;
    asm volatile("s_waitcnt lgkmcnt(0)" ::: "memory");
    __builtin_amdgcn_s_barrier();
    __builtin_amdgcn_sched_barrier(0);
    mfma_step(1);
  }
  #pragma unroll
  for (int mt = 0; mt < 2; mt++)
    #pragma unroll
    for (int nt = 0; nt < 2; nt++) {
      const int col = n0 + wc * 64 + nt * 32 + l31;
      const float bb = bias[col];
      #pragma unroll
      for (int r = 0; r < 16; r++) {
        int rowo = m0 + wr * 64 + mt * 32 + (r & 3) + 8 * (r >> 2) + 4 * hi;
        if (rowo < M) out[(size_t)rowo * N + col] = acc[mt][nt][r] + bb;
      }
    }
}

// ---------------- fused RMSNorm + RoPE + KV-window scatter ----------------
// Q is PRE-SCALED by (1/sqrt(128))*log2(e) so the attention kernel skips per-score scaling.
__launch_bounds__(256)
__global__ void k_norm_rope(const float* __restrict__ qp, const float* __restrict__ kp,
                            const float* __restrict__ vp, const float* __restrict__ gq,
                            const float* __restrict__ gk, const float* __restrict__ freqs,
                            const int* __restrict__ gs, const int* __restrict__ csp,
                            int S, int KVcap,
                            u16* __restrict__ rq, u16* __restrict__ K_all,
                            u16* __restrict__ VT) {
  const int t = blockIdx.x;
  const int tid = threadIdx.x;
  const float* q = qp + (size_t)t * MODEL_DIM;
  const float* k = kp + (size_t)t * MODEL_DIM;
  const float* v = vp + (size_t)t * MODEL_DIM;
  float sq = 0.f, sk = 0.f;
  for (int j = tid; j < MODEL_DIM; j += 256) {
    float a = q[j]; sq += a * a;
    float b = k[j]; sk += b * b;
  }
  #pragma unroll
  for (int off = 32; off > 0; off >>= 1) {
    sq += __shfl_down(sq, off, 64);
    sk += __shfl_down(sk, off, 64);
  }
  __shared__ float red[8];
  int wv_ = tid >> 6, l = tid & 63;
  if (l == 0) { red[wv_] = sq; red[4 + wv_] = sk; }
  __syncthreads();
  sq = red[0] + red[1] + red[2] + red[3];
  sk = red[4] + red[5] + red[6] + red[7];
  const float rq_s = rsqrtf(sq * (1.0f / MODEL_DIM) + 1e-6f) * 0.12751744f; // * (1/sqrt(128))*log2(e)
  const float rk_s = rsqrtf(sk * (1.0f / MODEL_DIM) + 1e-6f);

  const int cs = csp[0];
  const int h = gs[1], ww = gs[2];
  const int hw = h * ww;
  const int sf = cs / hw;                 // start_frame
  const int fi = t / hw;
  const int rr = t - fi * hw;
  const int hi = rr / ww;
  const int wi = rr - hi * ww;
  const int ce = cs + S;
  int wst = ce - MAX_ATTN_W; if (wst < 0) wst = 0;
  const int jj = cs + t - wst;

  for (int p = tid; p < NHEADS * 64; p += 256) {
    int n = p >> 6, c = p & 63;
    int pos = (c < 22) ? (sf + fi) : ((c < 43) ? hi : wi);
    float cv = freqs[(pos * 64 + c) * 2];
    float sv = freqs[(pos * 64 + c) * 2 + 1];
    int j0 = n * HDIM + 2 * c;
    float qr = q[j0] * rq_s * gq[j0];
    float qi = q[j0 + 1] * rq_s * gq[j0 + 1];
    *(u32*)(rq + ((size_t)n * S + t) * HDIM + 2 * c) = pk2(qr * cv - qi * sv, qr * sv + qi * cv);
    float kr = k[j0] * rk_s * gk[j0];
    float ki = k[j0 + 1] * rk_s * gk[j0 + 1];
    *(u32*)(K_all + ((size_t)n * KVcap + jj) * HDIM + 2 * c) = pk2(kr * cv - ki * sv, kr * sv + ki * cv);
  }
  for (int j = tid; j < MODEL_DIM; j += 256) {
    int n = j >> 7, d = j & 127;
    VT[((size_t)n * HDIM + d) * KVcap + jj] = f2bf(v[j]);
  }
}

// ---------------- flash attention, split-K, 32x32 MFMA, KVB=32 counted-vmcnt dbuf ----------------
// R19 form (120.5 us): KVB=32, 32KB dbuf, counted vmcnt(4), V swizzle ((row>>1)&3)<<3.
// This round: launch_bounds (256,3)->(256,4). 84 VGPR + 32KB LDS fit 4 blocks/CU
// (4x84=336<=512 VGPR/SIMD; 4x32KB=128<=160KB). Spill tripwire: WRITE_SIZE must stay ~49MB.
__launch_bounds__(256, 4)
__global__ void k_attn_split(const u16* __restrict__ rq, const u16* __restrict__ K_all,
                             const u16* __restrict__ VT,
                             u16* __restrict__ po, float* __restrict__ pm, float* __restrict__ pl,
                             const int* __restrict__ csp, int S, int KVcap, int nqb) {
  __shared__ __align__(16) u16 Klds[2][32][128];
  __shared__ __align__(16) u16 Vlds[2][128][32];

  const int tid = threadIdx.x;
  const int wid = tid >> 6;
  const int l = tid & 63;
  const int l31 = l & 31;
  const int hi = l >> 5;
  const int swz = (l31 & 7) << 3;

  // bijective XCD-grouped decode of (q-block, head, split); (NHEADS*NSPLIT)%8==0
  const int bx = blockIdx.x;
  const int xcd = bx & 7;
  const int j = bx >> 3;
  const int cl = j / nqb;
  const int qb = j - cl * nqb;
  const int chunkid = cl * 8 + xcd;
  const int head = chunkid / NSPLIT;
  const int split = chunkid - head * NSPLIT;
  const int q0 = qb * 128;

  const int cs = csp[0];
  const int ce = cs + S;
  int wst = ce - MAX_ATTN_W; if (wst < 0) wst = 0;
  const int KV = ce - wst;
  const int chunk = (((KV + NSPLIT - 1) / NSPLIT) + 31) & ~31;
  const int kstart = split * chunk;
  int kend = kstart + chunk; if (kend > KV) kend = KV;

  const size_t pbase = ((size_t)head * NSPLIT + split) * S;
  const int qrow = q0 + wid * 32 + l31;

  if (kstart >= kend) {
    if (qrow < S && hi == 0) { pm[pbase + qrow] = -3.0e38f; pl[pbase + qrow] = 0.f; }
    return;
  }

  // Q fragments: lane supplies Q[q=qrow][k = ds*16 + hi*8 + i] (B-frag of 32x32x16)
  bf16x8 qf[8];
  if (qrow < S) {
    const u16* qp = rq + ((size_t)head * S + qrow) * HDIM;
    #pragma unroll
    for (int ds = 0; ds < 8; ds++) qf[ds] = *(const bf16x8*)(qp + ds * 16 + hi * 8);
  } else {
    #pragma unroll
    for (int ds = 0; ds < 8; ds++)
      #pragma unroll
      for (int i = 0; i < 8; i++) qf[ds][i] = (__bf16)0.0f;
  }

  f32x16 o[4];
  #pragma unroll
  for (int dt = 0; dt < 4; dt++)
    #pragma unroll
    for (int j2 = 0; j2 < 16; j2++) o[dt][j2] = 0.f;
  float m_ = -3.0e38f, lsum_ = 0.f;

  const u16* Kh = K_all + (size_t)head * KVcap * HDIM;
  const u16* Vh = VT + (size_t)head * HDIM * KVcap;

  // Per-lane constant source offsets (pre-swizzled); LDS dest linear per buffer.
  int krow_i[2], kcol_i[2], vd_i[2], vcol_i[2];
  #pragma unroll
  for (int i = 0; i < 2; i++) {
    int gi = wid * 2 + i;                         // 0..7
    int kr_ = gi * 4 + (l >> 4);                  // K row 0..31
    krow_i[i] = kr_;
    kcol_i[i] = (((l & 15) ^ (kr_ & 7)) << 3);
    int vd_ = gi * 16 + (l >> 2);                 // V d-row 0..127
    vd_i[i] = vd_;
    vcol_i[i] = (((l & 3) ^ ((vd_ >> 1) & 3)) << 3);
  }

  const int ntiles = (kend - kstart + 31) >> 5;

  // issue one tile's gloads into buffer p (2 K + 2 V wave-instructions per wave)
  auto issue_tile = [&](int p, int key0) {
    u16* kbase = &Klds[p][0][0] + (wid * 2) * 512;
    u16* vbase = &Vlds[p][0][0] + (wid * 2) * 512;
    #pragma unroll
    for (int i = 0; i < 2; i++)
      gload_lds16(Kh + (size_t)(key0 + krow_i[i]) * HDIM + kcol_i[i], kbase + i * 512);
    #pragma unroll
    for (int i = 0; i < 2; i++)
      gload_lds16(Vh + (size_t)vd_i[i] * KVcap + key0 + vcol_i[i], vbase + i * 512);
  };

  issue_tile(0, kstart);   // prologue: tile 0 in flight (4 loads/wave)

  for (int t = 0; t < ntiles; t++) {
    const int key0 = kstart + (t << 5);
    const int cur = t & 1;

    if (t + 1 < ntiles) {
      issue_tile(cur ^ 1, key0 + 32);              // prefetch t+1 (stays in flight)
      __builtin_amdgcn_sched_barrier(0);
      asm volatile("s_waitcnt vmcnt(4)" ::: "memory");   // my t-loads landed
    } else {
      asm volatile("s_waitcnt vmcnt(0)" ::: "memory");
    }
    __builtin_amdgcn_s_barrier();                  // everyone's t-loads landed
    __builtin_amdgcn_sched_barrier(0);

    // QK^T swapped: s = S^T over keys [key0, key0+32), q = l31
    f32x16 s;
    __builtin_amdgcn_s_setprio(1);
    #pragma unroll
    for (int j2 = 0; j2 < 16; j2++) s[j2] = 0.f;
    #pragma unroll
    for (int ds = 0; ds < 8; ds++) {
      bf16x8 kf = *(const bf16x8*)&Klds[cur][l31][(ds * 16 + hi * 8) ^ swz];
      s = __builtin_amdgcn_mfma_f32_32x32x16_bf16(kf, qf[ds], s, 0, 0, 0);
    }
    __builtin_amdgcn_s_setprio(0);

    // row max (scores already in base-2 domain via pre-scaled Q)
    float tm = -3.0e38f;
    if (key0 + 32 <= kend) {
      #pragma unroll
      for (int r = 0; r < 16; r++) tm = fmaxf(tm, s[r]);
    } else {
      const int rem = kend - key0;
      #pragma unroll
      for (int r = 0; r < 16; r++) {
        const int off = (r & 3) + 8 * (r >> 2) + 4 * hi;
        float v = (off < rem) ? s[r] : -3.0e38f;
        s[r] = v;
        tm = fmaxf(tm, v);
      }
    }
    tm = fmaxf(tm, __shfl_xor(tm, 32, 64));

    // defer-max: only rescale when the running max grew by > 8 (P bounded by 2^8)
    if (!__all(tm <= m_ + 8.0f)) {
      float nm = fmaxf(m_, tm);
      float alpha = exp2f(m_ - nm);
      m_ = nm;
      lsum_ *= alpha;
      #pragma unroll
      for (int dt = 0; dt < 4; dt++)
        #pragma unroll
        for (int j2 = 0; j2 < 16; j2++) o[dt][j2] *= alpha;
    }

    float rs = 0.f;
    u32 w[8];
    #pragma unroll
    for (int j2 = 0; j2 < 8; j2++) {
      float p0 = exp2f(s[2 * j2] - m_);
      float p1 = exp2f(s[2 * j2 + 1] - m_);
      rs += p0 + p1;
      w[j2] = pk2(p0, p1);
    }
    rs += __shfl_xor(rs, 32, 64);
    lsum_ += rs;

    // assemble PV B-frags: half-exchange via shfl_xor(32), then per-half selects.
    union { u32 u[4]; bf16x8 v; } pf[2];
    {
      u32 xw[8];
      #pragma unroll
      for (int j2 = 0; j2 < 8; j2++) xw[j2] = __shfl_xor(w[j2], 32, 64);
      pf[0].u[0] = hi ? xw[2] : w[0];
      pf[0].u[1] = hi ? xw[3] : w[1];
      pf[0].u[2] = hi ? w[2]  : xw[0];
      pf[0].u[3] = hi ? w[3]  : xw[1];
      pf[1].u[0] = hi ? xw[6] : w[4];
      pf[1].u[1] = hi ? xw[7] : w[5];
      pf[1].u[2] = hi ? w[6]  : xw[4];
      pf[1].u[3] = hi ? w[7]  : xw[5];
    }

    // PV swapped: O^T[d][q] += V^T[d][key] * P[key][q]
    __builtin_amdgcn_s_setprio(1);
    #pragma unroll
    for (int dt = 0; dt < 4; dt++) {
      const int vrow = dt * 32 + l31;
      const int vswz = ((vrow >> 1) & 3) << 3;
      #pragma unroll
      for (int mm = 0; mm < 2; mm++) {
        bf16x8 vf = *(const bf16x8*)&Vlds[cur][vrow][(mm * 16 + hi * 8) ^ vswz];
        o[dt] = __builtin_amdgcn_mfma_f32_32x32x16_bf16(vf, pf[mm].v, o[dt], 0, 0, 0);
      }
    }
    __builtin_amdgcn_s_setprio(0);

    __builtin_amdgcn_sched_barrier(0);
    __builtin_amdgcn_s_barrier();   // all reads of buf[cur] done (next iter overwrites it)
  }

  // epilogue: q = qrow; d = dt*32 + 8*jj + (reg&3) + 4*hi
  if (qrow < S) {
    float rl = (lsum_ > 0.f) ? (1.0f / lsum_) : 0.f;
    u16* dst = po + (pbase + qrow) * HDIM;
    #pragma unroll
    for (int dt = 0; dt < 4; dt++)
      #pragma unroll
      for (int jj = 0; jj < 4; jj++) {
        u32 w0 = pk2(o[dt][4 * jj] * rl, o[dt][4 * jj + 1] * rl);
        u32 w1 = pk2(o[dt][4 * jj + 2] * rl, o[dt][4 * jj + 3] * rl);
        *(uint2*)(dst + dt * 32 + 8 * jj + 4 * hi) = make_uint2(w0, w1);
      }
    if (hi == 0) { pm[pbase + qrow] = m_; pl[pbase + qrow] = lsum_; }
  }
}

// ---------------- combine split-K partials (base-2 domain), 2 tokens/block ----------------
__launch_bounds__(256)
__global__ void k_attn_reduce(const u16* __restrict__ po, const float* __restrict__ pm,
                              const float* __restrict__ pl, u16* __restrict__ attn_out,
                              int S) {
  const int tb = blockIdx.x * 2 + (threadIdx.x >> 7);   // token
  const int h = blockIdx.y;
  const int d = threadIdx.x & 127;
  if (tb >= S) return;
  float ms[NSPLIT];
  float M = -3.0e38f;
  #pragma unroll
  for (int s = 0; s < NSPLIT; s++) {
    ms[s] = pm[((size_t)h * NSPLIT + s) * S + tb];
    M = fmaxf(M, ms[s]);
  }
  float L = 0.f, acc = 0.f;
  #pragma unroll
  for (int s = 0; s < NSPLIT; s++) {
    float wgt = exp2f(ms[s] - M) * pl[((size_t)h * NSPLIT + s) * S + tb];
    L += wgt;
    acc += wgt * bf2f(po[(((size_t)h * NSPLIT + s) * S + tb) * HDIM + d]);
  }
  attn_out[(size_t)tb * MODEL_DIM + h * HDIM + d] = f2bf(acc / L);
}

extern "C" void kernel_launch(void* const* d_in, const int* in_sizes, int n_in,
                              void* d_out, int out_size, void* d_ws, size_t ws_size,
                              hipStream_t stream) {
  (void)n_in; (void)out_size; (void)ws_size;
  const float* x  = (const float*)d_in[0];
  const float* wq = (const float*)d_in[1];
  const float* bq = (const float*)d_in[2];
  const float* wk = (const float*)d_in[3];
  const float* bk = (const float*)d_in[4];
  const float* wv = (const float*)d_in[5];
  const float* bv = (const float*)d_in[6];
  const float* wo = (const float*)d_in[7];
  const float* bo = (const float*)d_in[8];
  const float* gq = (const float*)d_in[9];
  const float* gk = (const float*)d_in[10];
  const float* freqs = (const float*)d_in[11];
  const float* k_cache = (const float*)d_in[12];
  const float* v_cache = (const float*)d_in[13];
  const int* gs  = (const int*)d_in[14];
  const int* csp = (const int*)d_in[15];

  const int S = in_sizes[0] / MODEL_DIM;
  const int CACHE = in_sizes[12] / (NHEADS * HDIM);
  const int KVcap = (CACHE < MAX_ATTN_W) ? CACHE : MAX_ATTN_W;
  const int Mpad = (S + 127) & ~127;
  const int NQB = Mpad / 128;

  char* ws = (char*)d_ws;
  size_t off = 0;
  auto alloc = [&](size_t bytes) {
    char* p = ws + off;
    off += (bytes + 255) & ~(size_t)255;
    return p;
  };
  u16* xb   = (u16*)alloc((size_t)Mpad * MODEL_DIM * 2);
  u16* wqb  = (u16*)alloc((size_t)MODEL_DIM * MODEL_DIM * 2);
  u16* wkb  = (u16*)alloc((size_t)MODEL_DIM * MODEL_DIM * 2);
  u16* wvb  = (u16*)alloc((size_t)MODEL_DIM * MODEL_DIM * 2);
  u16* wob  = (u16*)alloc((size_t)MODEL_DIM * MODEL_DIM * 2);
  float* q_pre = (float*)alloc((size_t)S * MODEL_DIM * 4);
  float* k_pre = (float*)alloc((size_t)S * MODEL_DIM * 4);
  float* v_pre = (float*)alloc((size_t)S * MODEL_DIM * 4);
  u16* rqb   = (u16*)alloc((size_t)NHEADS * S * HDIM * 2);
  u16* K_all = (u16*)alloc((size_t)NHEADS * KVcap * HDIM * 2);
  u16* VT    = (u16*)alloc((size_t)NHEADS * HDIM * KVcap * 2);
  u16* attn_o = (u16*)alloc((size_t)Mpad * MODEL_DIM * 2);
  u16* po    = (u16*)alloc((size_t)NHEADS * NSPLIT * S * HDIM * 2);
  float* pm  = (float*)alloc((size_t)NHEADS * NSPLIT * S * 4);
  float* pl  = (float*)alloc((size_t)NHEADS * NSPLIT * S * 4);

  const int nx4 = S * MODEL_DIM / 4;
  const int nw4 = MODEL_DIM * MODEL_DIM / 4;
  const int njb = (KVcap + 63) / 64;
  int gx = njb * NHEADS;
  if (gx < (nw4 + 255) / 256) gx = (nw4 + 255) / 256;
  if (gx < (nx4 + 255) / 256) gx = (nx4 + 255) / 256;

  // one fused prep launch: converts + K window + V^T window
  hipLaunchKernelGGL(k_prep, dim3(gx, 7), dim3(256), 0, stream,
                     x, nx4, wq, wk, wv, wo, nw4, xb, wqb, wkb, wvb, wob,
                     k_cache, v_cache, K_all, VT, csp, S, KVcap);

  hipLaunchKernelGGL(k_gemm_qkv128, dim3(Mpad / 128, 3 * MODEL_DIM / 128), dim3(256), 0, stream,
                     xb, wqb, wkb, wvb, bq, bk, bv, q_pre, k_pre, v_pre, S, MODEL_DIM, MODEL_DIM);

  hipLaunchKernelGGL(k_norm_rope, dim3(S), dim3(256), 0, stream,
                     q_pre, k_pre, v_pre, gq, gk, freqs, gs, csp, S, KVcap, rqb, K_all, VT);

  // flat grid: NQB * NHEADS * NSPLIT; (NHEADS*NSPLIT)%8==0 -> bijective XCD grouping
  hipLaunchKernelGGL(k_attn_split, dim3(NQB * NHEADS * NSPLIT), dim3(256), 0, stream,
                     rqb, K_all, VT, po, pm, pl, csp, S, KVcap, NQB);

  hipLaunchKernelGGL(k_attn_reduce, dim3((S + 1) / 2, NHEADS), dim3(256), 0, stream,
                     po, pm, pl, attn_o, S);

  hipLaunchKernelGGL(k_gemm_o128, dim3(Mpad / 128, MODEL_DIM / 128), dim3(256), 0, stream,
                     attn_o, wob, bo, (float*)d_out, S, MODEL_DIM, MODEL_DIM);
}

// Round 21
// 276.327 us; speedup vs baseline: 1.3022x; 1.3022x over previous
//
#include <hip/hip_runtime.h>

#define NHEADS 12
#define HDIM 128
#define MODEL_DIM 1536
#define MAX_ATTN_W 13200
#define NSPLIT 18

typedef unsigned short u16;
typedef unsigned int u32;
typedef float f32x4 __attribute__((ext_vector_type(4)));
typedef float f32x16 __attribute__((ext_vector_type(16)));
typedef __bf16 bf16x8 __attribute__((ext_vector_type(8)));

static __device__ __forceinline__ u16 f2bf(float f) {
  union { __bf16 h; u16 u; } cv;
  cv.h = (__bf16)f;
  return cv.u;
}
static __device__ __forceinline__ float bf2f(u16 u) {
  union { u32 u; float f; } cv;
  cv.u = ((u32)u) << 16;
  return cv.f;
}
static __device__ __forceinline__ u32 pk2(float a, float b) {
  return (u32)f2bf(a) | ((u32)f2bf(b) << 16);
}
// async global->LDS, 16B per lane; LDS dest = wave-uniform base + lane*16
static __device__ __forceinline__ void gload_lds16(const void* g, void* l) {
  __builtin_amdgcn_global_load_lds(
      (const __attribute__((address_space(1))) unsigned int*)g,
      (__attribute__((address_space(3))) unsigned int*)l, 16, 0, 0);
}

// ---------------- fused prep: converts + K-window + V^T-window in ONE launch ----------------
__launch_bounds__(256)
__global__ void k_prep(const float* __restrict__ x, int nx4,
                       const float* __restrict__ wq, const float* __restrict__ wk,
                       const float* __restrict__ wv, const float* __restrict__ wo, int nw4,
                       u16* __restrict__ xb, u16* __restrict__ wqb, u16* __restrict__ wkb,
                       u16* __restrict__ wvb, u16* __restrict__ wob,
                       const float* __restrict__ kc, const float* __restrict__ vc,
                       u16* __restrict__ K_all, u16* __restrict__ VT,
                       const int* __restrict__ csp, int S, int KVcap) {
  const int tid = threadIdx.x;
  const int which = blockIdx.y;

  if (which <= 4) {
    const float* src = (which == 0) ? x : (which == 1) ? wq : (which == 2) ? wk
                       : (which == 3) ? wv : wo;
    u16* dst = (which == 0) ? xb : (which == 1) ? wqb : (which == 2) ? wkb
               : (which == 3) ? wvb : wob;
    const int n4 = (which == 0) ? nx4 : nw4;
    for (int i = blockIdx.x * 256 + tid; i < n4; i += gridDim.x * 256) {
      float4 v = ((const float4*)src)[i];
      ((uint2*)dst)[i] = make_uint2(pk2(v.x, v.y), pk2(v.z, v.w));
    }
    return;
  }

  const int cs = csp[0];
  const int ce = cs + S;
  int wst = ce - MAX_ATTN_W; if (wst < 0) wst = 0;
  const int oldlen = cs - wst;

  if (which == 5) {
    const long per = (long)oldlen * 16;   // 16 chunks of 8 along d
    const long total = per * NHEADS;
    for (long c = blockIdx.x * 256L + tid; c < total; c += (long)gridDim.x * 256) {
      int n = (int)(c / per);
      long r = c - (long)n * per;
      int jo = (int)(r >> 4);
      int dc = ((int)r & 15) * 8;
      const float* s = kc + ((size_t)(wst + jo) * NHEADS + n) * HDIM + dc;
      float4 a = *(const float4*)s;
      float4 b = *(const float4*)(s + 4);
      uint4 o;
      o.x = pk2(a.x, a.y);
      o.y = pk2(a.z, a.w);
      o.z = pk2(b.x, b.y);
      o.w = pk2(b.z, b.w);
      *(uint4*)(K_all + ((size_t)n * KVcap + jo) * HDIM + dc) = o;
    }
    return;
  }

  // which == 6: V^T window [n][d][jj] via LDS tile transpose (64 j x 128 d per block)
  __shared__ u16 tile[64][130];
  const int njb = (KVcap + 63) >> 6;
  const int bx = blockIdx.x;
  if (bx >= njb * NHEADS) return;
  const int n = bx / njb;
  const int j0 = (bx - n * njb) * 64;
  if (j0 >= oldlen) return;

  #pragma unroll
  for (int i = 0; i < 8; i++) {
    int idx = tid + 256 * i;
    int jr = idx >> 5;
    int dc = (idx & 31) * 4;
    float4 v = make_float4(0.f, 0.f, 0.f, 0.f);
    if (j0 + jr < oldlen)
      v = *(const float4*)(vc + ((size_t)(wst + j0 + jr) * NHEADS + n) * HDIM + dc);
    *(u32*)&tile[jr][dc] = pk2(v.x, v.y);
    *(u32*)&tile[jr][dc + 2] = pk2(v.z, v.w);
  }
  __syncthreads();

  const int d = tid >> 1;
  const int jh = (tid & 1) * 32;
  alignas(16) u16 buf[32];
  #pragma unroll
  for (int jr = 0; jr < 32; jr++) buf[jr] = tile[jh + jr][d];
  u16* dst = VT + ((size_t)n * HDIM + d) * KVcap + j0 + jh;
  if (j0 + jh + 32 <= oldlen) {
    #pragma unroll
    for (int c = 0; c < 4; c++)
      *(uint4*)(dst + c * 8) = *(const uint4*)&buf[c * 8];
  } else {
    for (int jr = 0; jr < 32 && j0 + jh + jr < oldlen; jr++) dst[jr] = buf[jr];
  }
}

// ---------------- out-proj GEMM, 128x128 tile, counted-vmcnt dbuf (1 barrier/K-step) ----------------
__launch_bounds__(256)
__global__ void k_gemm_o128(const u16* __restrict__ A, const u16* __restrict__ B,
                            const float* __restrict__ bias, float* __restrict__ out,
                            int M, int N, int K) {
  __shared__ __align__(16) u16 Al[2][128][40];
  __shared__ __align__(16) u16 Bl[2][128][40];
  const int n0 = blockIdx.y * 128;
  const int tid = threadIdx.x;
  const int wid = tid >> 6, l = tid & 63, l31 = l & 31, hi = l >> 5;
  const int wr = wid >> 1, wc = wid & 1;
  const int m0 = blockIdx.x * 128;
  f32x16 acc[2][2];
  #pragma unroll
  for (int mt = 0; mt < 2; mt++)
    #pragma unroll
    for (int nt = 0; nt < 2; nt++)
      #pragma unroll
      for (int j = 0; j < 16; j++) acc[mt][nt][j] = 0.f;
  const int row = tid >> 2, colc = (tid & 3) * 8;
  const u16* Ar0 = A + (size_t)(m0 + row) * K + colc;
  const u16* Ar1 = A + (size_t)(m0 + row + 64) * K + colc;
  const u16* Br0 = B + (size_t)(n0 + row) * K + colc;
  const u16* Br1 = B + (size_t)(n0 + row + 64) * K + colc;

  uint4 ra0, ra1, ra2, ra3, rb0, rb1, rb2, rb3;
  auto loadA = [&](int k0) {
    ra0 = *(const uint4*)(Ar0 + k0); ra1 = *(const uint4*)(Ar1 + k0);
    ra2 = *(const uint4*)(Br0 + k0); ra3 = *(const uint4*)(Br1 + k0);
  };
  auto loadB = [&](int k0) {
    rb0 = *(const uint4*)(Ar0 + k0); rb1 = *(const uint4*)(Ar1 + k0);
    rb2 = *(const uint4*)(Br0 + k0); rb3 = *(const uint4*)(Br1 + k0);
  };
  auto mfma_step = [&](int p) {
    #pragma unroll
    for (int ks = 0; ks < 2; ks++) {
      bf16x8 af[2], bfr[2];
      #pragma unroll
      for (int mt = 0; mt < 2; mt++)
        af[mt] = *(const bf16x8*)&Al[p][wr * 64 + mt * 32 + l31][ks * 16 + hi * 8];
      #pragma unroll
      for (int nt = 0; nt < 2; nt++)
        bfr[nt] = *(const bf16x8*)&Bl[p][wc * 64 + nt * 32 + l31][ks * 16 + hi * 8];
      #pragma unroll
      for (int mt = 0; mt < 2; mt++)
        #pragma unroll
        for (int nt = 0; nt < 2; nt++)
          acc[mt][nt] = __builtin_amdgcn_mfma_f32_32x32x16_bf16(af[mt], bfr[nt], acc[mt][nt], 0, 0, 0);
    }
  };

  const int nk = K / 32;   // even
  loadA(0);
  for (int t = 0; t < nk; t += 2) {
    const int k0 = t * 32;
    if (t + 1 < nk) loadB(k0 + 32);
    __builtin_amdgcn_sched_barrier(0);
    if (t + 1 < nk) asm volatile("s_waitcnt vmcnt(4)" ::: "memory");
    else            asm volatile("s_waitcnt vmcnt(0)" ::: "memory");
    __builtin_amdgcn_sched_barrier(0);
    *(uint4*)&Al[0][row][colc] = ra0;
    *(uint4*)&Al[0][row + 64][colc] = ra1;
    *(uint4*)&Bl[0][row][colc] = ra2;
    *(uint4*)&Bl[0][row + 64][colc] = ra3;
    asm volatile("s_waitcnt lgkmcnt(0)" ::: "memory");
    __builtin_amdgcn_s_barrier();
    __builtin_amdgcn_sched_barrier(0);
    mfma_step(0);
    if (t + 2 < nk) loadA(k0 + 64);
    __builtin_amdgcn_sched_barrier(0);
    if (t + 2 < nk) asm volatile("s_waitcnt vmcnt(4)" ::: "memory");
    else            asm volatile("s_waitcnt vmcnt(0)" ::: "memory");
    __builtin_amdgcn_sched_barrier(0);
    *(uint4*)&Al[1][row][colc] = rb0;
    *(uint4*)&Al[1][row + 64][colc] = rb1;
    *(uint4*)&Bl[1][row][colc] = rb2;
    *(uint4*)&Bl[1][row + 64][colc] = rb3;
    asm volatile("s_waitcnt lgkmcnt(0)" ::: "memory");
    __builtin_amdgcn_s_barrier();
    __builtin_amdgcn_sched_barrier(0);
    mfma_step(1);
  }
  #pragma unroll
  for (int mt = 0; mt < 2; mt++)
    #pragma unroll
    for (int nt = 0; nt < 2; nt++) {
      const int col = n0 + wc * 64 + nt * 32 + l31;
      const float bb = bias[col];
      #pragma unroll
      for (int r = 0; r < 16; r++) {
        int rowo = m0 + wr * 64 + mt * 32 + (r & 3) + 8 * (r >> 2) + 4 * hi;
        if (rowo < M) out[(size_t)rowo * N + col] = acc[mt][nt][r] + bb;
      }
    }
}

// ---------------- fused QKV GEMM, 128x128 tile, counted-vmcnt dbuf (1 barrier/K-step) ----------------
__launch_bounds__(256)
__global__ void k_gemm_qkv128(const u16* __restrict__ A,
                              const u16* __restrict__ B0, const u16* __restrict__ B1,
                              const u16* __restrict__ B2,
                              const float* __restrict__ bias0, const float* __restrict__ bias1,
                              const float* __restrict__ bias2,
                              float* __restrict__ o0, float* __restrict__ o1, float* __restrict__ o2,
                              int M, int N, int K) {
  __shared__ __align__(16) u16 Al[2][128][40];
  __shared__ __align__(16) u16 Bl[2][128][40];
  const int nblk = N / 128;
  const int which = blockIdx.y / nblk;
  const int n0 = (blockIdx.y % nblk) * 128;
  const u16* B = (which == 0) ? B0 : ((which == 1) ? B1 : B2);
  const float* bias = (which == 0) ? bias0 : ((which == 1) ? bias1 : bias2);
  float* out = (which == 0) ? o0 : ((which == 1) ? o1 : o2);
  const int tid = threadIdx.x;
  const int wid = tid >> 6, l = tid & 63, l31 = l & 31, hi = l >> 5;
  const int wr = wid >> 1, wc = wid & 1;
  const int m0 = blockIdx.x * 128;
  f32x16 acc[2][2];
  #pragma unroll
  for (int mt = 0; mt < 2; mt++)
    #pragma unroll
    for (int nt = 0; nt < 2; nt++)
      #pragma unroll
      for (int j = 0; j < 16; j++) acc[mt][nt][j] = 0.f;
  const int row = tid >> 2, colc = (tid & 3) * 8;
  const u16* Ar0 = A + (size_t)(m0 + row) * K + colc;
  const u16* Ar1 = A + (size_t)(m0 + row + 64) * K + colc;
  const u16* Br0 = B + (size_t)(n0 + row) * K + colc;
  const u16* Br1 = B + (size_t)(n0 + row + 64) * K + colc;

  uint4 ra0, ra1, ra2, ra3, rb0, rb1, rb2, rb3;
  auto loadA = [&](int k0) {
    ra0 = *(const uint4*)(Ar0 + k0); ra1 = *(const uint4*)(Ar1 + k0);
    ra2 = *(const uint4*)(Br0 + k0); ra3 = *(const uint4*)(Br1 + k0);
  };
  auto loadB = [&](int k0) {
    rb0 = *(const uint4*)(Ar0 + k0); rb1 = *(const uint4*)(Ar1 + k0);
    rb2 = *(const uint4*)(Br0 + k0); rb3 = *(const uint4*)(Br1 + k0);
  };
  auto mfma_step = [&](int p) {
    #pragma unroll
    for (int ks = 0; ks < 2; ks++) {
      bf16x8 af[2], bfr[2];
      #pragma unroll
      for (int mt = 0; mt < 2; mt++)
        af[mt] = *(const bf16x8*)&Al[p][wr * 64 + mt * 32 + l31][ks * 16 + hi * 8];
      #pragma unroll
      for (int nt = 0; nt < 2; nt++)
        bfr[nt] = *(const bf16x8*)&Bl[p][wc * 64 + nt * 32 + l31][ks * 16 + hi * 8];
      #pragma unroll
      for (int mt = 0; mt < 2; mt++)
        #pragma unroll
        for (int nt = 0; nt < 2; nt++)
          acc[mt][nt] = __builtin_amdgcn_mfma_f32_32x32x16_bf16(af[mt], bfr[nt], acc[mt][nt], 0, 0, 0);
    }
  };

  const int nk = K / 32;   // even
  loadA(0);
  for (int t = 0; t < nk; t += 2) {
    const int k0 = t * 32;
    if (t + 1 < nk) loadB(k0 + 32);
    __builtin_amdgcn_sched_barrier(0);
    if (t + 1 < nk) asm volatile("s_waitcnt vmcnt(4)" ::: "memory");
    else            asm volatile("s_waitcnt vmcnt(0)" ::: "memory");
    __builtin_amdgcn_sched_barrier(0);
    *(uint4*)&Al[0][row][colc] = ra0;
    *(uint4*)&Al[0][row + 64][colc] = ra1;
    *(uint4*)&Bl[0][row][colc] = ra2;
    *(uint4*)&Bl[0][row + 64][colc] = ra3;
    asm volatile("s_waitcnt lgkmcnt(0)" ::: "memory");
    __builtin_amdgcn_s_barrier();
    __builtin_amdgcn_sched_barrier(0);
    mfma_step(0);
    if (t + 2 < nk) loadA(k0 + 64);
    __builtin_amdgcn_sched_barrier(0);
    if (t + 2 < nk) asm volatile("s_waitcnt vmcnt(4)" ::: "memory");
    else            asm volatile("s_waitcnt vmcnt(0)" ::: "memory");
    __builtin_amdgcn_sched_barrier(0);
    *(uint4*)&Al[1][row][colc] = rb0;
    *(uint4*)&Al[1][row + 64][colc] = rb1;
    *(uint4*)&Bl[1][row][colc] = rb2;
    *(uint4*)&Bl[1][row + 64][colc] = rb3;
    asm volatile("s_waitcnt lgkmcnt(0)" ::: "memory");
    __builtin_amdgcn_s_barrier();
    __builtin_amdgcn_sched_barrier(0);
    mfma_step(1);
  }
  #pragma unroll
  for (int mt = 0; mt < 2; mt++)
    #pragma unroll
    for (int nt = 0; nt < 2; nt++) {
      const int col = n0 + wc * 64 + nt * 32 + l31;
      const float bb = bias[col];
      #pragma unroll
      for (int r = 0; r < 16; r++) {
        int rowo = m0 + wr * 64 + mt * 32 + (r & 3) + 8 * (r >> 2) + 4 * hi;
        if (rowo < M) out[(size_t)rowo * N + col] = acc[mt][nt][r] + bb;
      }
    }
}

// ---------------- fused RMSNorm + RoPE + KV-window scatter ----------------
// Q is PRE-SCALED by (1/sqrt(128))*log2(e) so the attention kernel skips per-score scaling.
__launch_bounds__(256)
__global__ void k_norm_rope(const float* __restrict__ qp, const float* __restrict__ kp,
                            const float* __restrict__ vp, const float* __restrict__ gq,
                            const float* __restrict__ gk, const float* __restrict__ freqs,
                            const int* __restrict__ gs, const int* __restrict__ csp,
                            int S, int KVcap,
                            u16* __restrict__ rq, u16* __restrict__ K_all,
                            u16* __restrict__ VT) {
  const int t = blockIdx.x;
  const int tid = threadIdx.x;
  const float* q = qp + (size_t)t * MODEL_DIM;
  const float* k = kp + (size_t)t * MODEL_DIM;
  const float* v = vp + (size_t)t * MODEL_DIM;
  float sq = 0.f, sk = 0.f;
  for (int j = tid; j < MODEL_DIM; j += 256) {
    float a = q[j]; sq += a * a;
    float b = k[j]; sk += b * b;
  }
  #pragma unroll
  for (int off = 32; off > 0; off >>= 1) {
    sq += __shfl_down(sq, off, 64);
    sk += __shfl_down(sk, off, 64);
  }
  __shared__ float red[8];
  int wv_ = tid >> 6, l = tid & 63;
  if (l == 0) { red[wv_] = sq; red[4 + wv_] = sk; }
  __syncthreads();
  sq = red[0] + red[1] + red[2] + red[3];
  sk = red[4] + red[5] + red[6] + red[7];
  const float rq_s = rsqrtf(sq * (1.0f / MODEL_DIM) + 1e-6f) * 0.12751744f; // * (1/sqrt(128))*log2(e)
  const float rk_s = rsqrtf(sk * (1.0f / MODEL_DIM) + 1e-6f);

  const int cs = csp[0];
  const int h = gs[1], ww = gs[2];
  const int hw = h * ww;
  const int sf = cs / hw;                 // start_frame
  const int fi = t / hw;
  const int rr = t - fi * hw;
  const int hi = rr / ww;
  const int wi = rr - hi * ww;
  const int ce = cs + S;
  int wst = ce - MAX_ATTN_W; if (wst < 0) wst = 0;
  const int jj = cs + t - wst;

  for (int p = tid; p < NHEADS * 64; p += 256) {
    int n = p >> 6, c = p & 63;
    int pos = (c < 22) ? (sf + fi) : ((c < 43) ? hi : wi);
    float cv = freqs[(pos * 64 + c) * 2];
    float sv = freqs[(pos * 64 + c) * 2 + 1];
    int j0 = n * HDIM + 2 * c;
    float qr = q[j0] * rq_s * gq[j0];
    float qi = q[j0 + 1] * rq_s * gq[j0 + 1];
    *(u32*)(rq + ((size_t)n * S + t) * HDIM + 2 * c) = pk2(qr * cv - qi * sv, qr * sv + qi * cv);
    float kr = k[j0] * rk_s * gk[j0];
    float ki = k[j0 + 1] * rk_s * gk[j0 + 1];
    *(u32*)(K_all + ((size_t)n * KVcap + jj) * HDIM + 2 * c) = pk2(kr * cv - ki * sv, kr * sv + ki * cv);
  }
  for (int j = tid; j < MODEL_DIM; j += 256) {
    int n = j >> 7, d = j & 127;
    VT[((size_t)n * HDIM + d) * KVcap + jj] = f2bf(v[j]);
  }
}

// ---------------- flash attention, split-K, 32x32 MFMA, KVB=32 counted-vmcnt dbuf ----------------
// R19 configuration (proven best: attn 120.5 us, total 277.2): KVB=32, 32KB dbuf,
// counted vmcnt(4), V swizzle ((row>>1)&3)<<3, launch_bounds (256,3) -> 84 VGPR, no spill.
// R20's (256,4) REGRESSED (VGPR capped to 64 -> spills, WRITE 49->87MB, attn 208us).
// Occupancy ladder measured: 2 blk=129us (R18), 3 blk=120.5us (R19, optimum), 4 blk=spill.
__launch_bounds__(256, 3)
__global__ void k_attn_split(const u16* __restrict__ rq, const u16* __restrict__ K_all,
                             const u16* __restrict__ VT,
                             u16* __restrict__ po, float* __restrict__ pm, float* __restrict__ pl,
                             const int* __restrict__ csp, int S, int KVcap, int nqb) {
  __shared__ __align__(16) u16 Klds[2][32][128];
  __shared__ __align__(16) u16 Vlds[2][128][32];

  const int tid = threadIdx.x;
  const int wid = tid >> 6;
  const int l = tid & 63;
  const int l31 = l & 31;
  const int hi = l >> 5;
  const int swz = (l31 & 7) << 3;

  // bijective XCD-grouped decode of (q-block, head, split); (NHEADS*NSPLIT)%8==0
  const int bx = blockIdx.x;
  const int xcd = bx & 7;
  const int j = bx >> 3;
  const int cl = j / nqb;
  const int qb = j - cl * nqb;
  const int chunkid = cl * 8 + xcd;
  const int head = chunkid / NSPLIT;
  const int split = chunkid - head * NSPLIT;
  const int q0 = qb * 128;

  const int cs = csp[0];
  const int ce = cs + S;
  int wst = ce - MAX_ATTN_W; if (wst < 0) wst = 0;
  const int KV = ce - wst;
  const int chunk = (((KV + NSPLIT - 1) / NSPLIT) + 31) & ~31;
  const int kstart = split * chunk;
  int kend = kstart + chunk; if (kend > KV) kend = KV;

  const size_t pbase = ((size_t)head * NSPLIT + split) * S;
  const int qrow = q0 + wid * 32 + l31;

  if (kstart >= kend) {
    if (qrow < S && hi == 0) { pm[pbase + qrow] = -3.0e38f; pl[pbase + qrow] = 0.f; }
    return;
  }

  // Q fragments: lane supplies Q[q=qrow][k = ds*16 + hi*8 + i] (B-frag of 32x32x16)
  bf16x8 qf[8];
  if (qrow < S) {
    const u16* qp = rq + ((size_t)head * S + qrow) * HDIM;
    #pragma unroll
    for (int ds = 0; ds < 8; ds++) qf[ds] = *(const bf16x8*)(qp + ds * 16 + hi * 8);
  } else {
    #pragma unroll
    for (int ds = 0; ds < 8; ds++)
      #pragma unroll
      for (int i = 0; i < 8; i++) qf[ds][i] = (__bf16)0.0f;
  }

  f32x16 o[4];
  #pragma unroll
  for (int dt = 0; dt < 4; dt++)
    #pragma unroll
    for (int j2 = 0; j2 < 16; j2++) o[dt][j2] = 0.f;
  float m_ = -3.0e38f, lsum_ = 0.f;

  const u16* Kh = K_all + (size_t)head * KVcap * HDIM;
  const u16* Vh = VT + (size_t)head * HDIM * KVcap;

  // Per-lane constant source offsets (pre-swizzled); LDS dest linear per buffer.
  int krow_i[2], kcol_i[2], vd_i[2], vcol_i[2];
  #pragma unroll
  for (int i = 0; i < 2; i++) {
    int gi = wid * 2 + i;                         // 0..7
    int kr_ = gi * 4 + (l >> 4);                  // K row 0..31
    krow_i[i] = kr_;
    kcol_i[i] = (((l & 15) ^ (kr_ & 7)) << 3);
    int vd_ = gi * 16 + (l >> 2);                 // V d-row 0..127
    vd_i[i] = vd_;
    vcol_i[i] = (((l & 3) ^ ((vd_ >> 1) & 3)) << 3);
  }

  const int ntiles = (kend - kstart + 31) >> 5;

  // issue one tile's gloads into buffer p (2 K + 2 V wave-instructions per wave)
  auto issue_tile = [&](int p, int key0) {
    u16* kbase = &Klds[p][0][0] + (wid * 2) * 512;
    u16* vbase = &Vlds[p][0][0] + (wid * 2) * 512;
    #pragma unroll
    for (int i = 0; i < 2; i++)
      gload_lds16(Kh + (size_t)(key0 + krow_i[i]) * HDIM + kcol_i[i], kbase + i * 512);
    #pragma unroll
    for (int i = 0; i < 2; i++)
      gload_lds16(Vh + (size_t)vd_i[i] * KVcap + key0 + vcol_i[i], vbase + i * 512);
  };

  issue_tile(0, kstart);   // prologue: tile 0 in flight (4 loads/wave)

  for (int t = 0; t < ntiles; t++) {
    const int key0 = kstart + (t << 5);
    const int cur = t & 1;

    if (t + 1 < ntiles) {
      issue_tile(cur ^ 1, key0 + 32);              // prefetch t+1 (stays in flight)
      __builtin_amdgcn_sched_barrier(0);
      asm volatile("s_waitcnt vmcnt(4)" ::: "memory");   // my t-loads landed
    } else {
      asm volatile("s_waitcnt vmcnt(0)" ::: "memory");
    }
    __builtin_amdgcn_s_barrier();                  // everyone's t-loads landed
    __builtin_amdgcn_sched_barrier(0);

    // QK^T swapped: s = S^T over keys [key0, key0+32), q = l31
    f32x16 s;
    __builtin_amdgcn_s_setprio(1);
    #pragma unroll
    for (int j2 = 0; j2 < 16; j2++) s[j2] = 0.f;
    #pragma unroll
    for (int ds = 0; ds < 8; ds++) {
      bf16x8 kf = *(const bf16x8*)&Klds[cur][l31][(ds * 16 + hi * 8) ^ swz];
      s = __builtin_amdgcn_mfma_f32_32x32x16_bf16(kf, qf[ds], s, 0, 0, 0);
    }
    __builtin_amdgcn_s_setprio(0);

    // row max (scores already in base-2 domain via pre-scaled Q)
    float tm = -3.0e38f;
    if (key0 + 32 <= kend) {
      #pragma unroll
      for (int r = 0; r < 16; r++) tm = fmaxf(tm, s[r]);
    } else {
      const int rem = kend - key0;
      #pragma unroll
      for (int r = 0; r < 16; r++) {
        const int off = (r & 3) + 8 * (r >> 2) + 4 * hi;
        float v = (off < rem) ? s[r] : -3.0e38f;
        s[r] = v;
        tm = fmaxf(tm, v);
      }
    }
    tm = fmaxf(tm, __shfl_xor(tm, 32, 64));

    // defer-max: only rescale when the running max grew by > 8 (P bounded by 2^8)
    if (!__all(tm <= m_ + 8.0f)) {
      float nm = fmaxf(m_, tm);
      float alpha = exp2f(m_ - nm);
      m_ = nm;
      lsum_ *= alpha;
      #pragma unroll
      for (int dt = 0; dt < 4; dt++)
        #pragma unroll
        for (int j2 = 0; j2 < 16; j2++) o[dt][j2] *= alpha;
    }

    float rs = 0.f;
    u32 w[8];
    #pragma unroll
    for (int j2 = 0; j2 < 8; j2++) {
      float p0 = exp2f(s[2 * j2] - m_);
      float p1 = exp2f(s[2 * j2 + 1] - m_);
      rs += p0 + p1;
      w[j2] = pk2(p0, p1);
    }
    rs += __shfl_xor(rs, 32, 64);
    lsum_ += rs;

    // assemble PV B-frags: half-exchange via shfl_xor(32), then per-half selects.
    union { u32 u[4]; bf16x8 v; } pf[2];
    {
      u32 xw[8];
      #pragma unroll
      for (int j2 = 0; j2 < 8; j2++) xw[j2] = __shfl_xor(w[j2], 32, 64);
      pf[0].u[0] = hi ? xw[2] : w[0];
      pf[0].u[1] = hi ? xw[3] : w[1];
      pf[0].u[2] = hi ? w[2]  : xw[0];
      pf[0].u[3] = hi ? w[3]  : xw[1];
      pf[1].u[0] = hi ? xw[6] : w[4];
      pf[1].u[1] = hi ? xw[7] : w[5];
      pf[1].u[2] = hi ? w[6]  : xw[4];
      pf[1].u[3] = hi ? w[7]  : xw[5];
    }

    // PV swapped: O^T[d][q] += V^T[d][key] * P[key][q]
    __builtin_amdgcn_s_setprio(1);
    #pragma unroll
    for (int dt = 0; dt < 4; dt++) {
      const int vrow = dt * 32 + l31;
      const int vswz = ((vrow >> 1) & 3) << 3;
      #pragma unroll
      for (int mm = 0; mm < 2; mm++) {
        bf16x8 vf = *(const bf16x8*)&Vlds[cur][vrow][(mm * 16 + hi * 8) ^ vswz];
        o[dt] = __builtin_amdgcn_mfma_f32_32x32x16_bf16(vf, pf[mm].v, o[dt], 0, 0, 0);
      }
    }
    __builtin_amdgcn_s_setprio(0);

    __builtin_amdgcn_sched_barrier(0);
    __builtin_amdgcn_s_barrier();   // all reads of buf[cur] done (next iter overwrites it)
  }

  // epilogue: q = qrow; d = dt*32 + 8*jj + (reg&3) + 4*hi
  if (qrow < S) {
    float rl = (lsum_ > 0.f) ? (1.0f / lsum_) : 0.f;
    u16* dst = po + (pbase + qrow) * HDIM;
    #pragma unroll
    for (int dt = 0; dt < 4; dt++)
      #pragma unroll
      for (int jj = 0; jj < 4; jj++) {
        u32 w0 = pk2(o[dt][4 * jj] * rl, o[dt][4 * jj + 1] * rl);
        u32 w1 = pk2(o[dt][4 * jj + 2] * rl, o[dt][4 * jj + 3] * rl);
        *(uint2*)(dst + dt * 32 + 8 * jj + 4 * hi) = make_uint2(w0, w1);
      }
    if (hi == 0) { pm[pbase + qrow] = m_; pl[pbase + qrow] = lsum_; }
  }
}

// ---------------- combine split-K partials (base-2 domain), 2 tokens/block ----------------
__launch_bounds__(256)
__global__ void k_attn_reduce(const u16* __restrict__ po, const float* __restrict__ pm,
                              const float* __restrict__ pl, u16* __restrict__ attn_out,
                              int S) {
  const int tb = blockIdx.x * 2 + (threadIdx.x >> 7);   // token
  const int h = blockIdx.y;
  const int d = threadIdx.x & 127;
  if (tb >= S) return;
  float ms[NSPLIT];
  float M = -3.0e38f;
  #pragma unroll
  for (int s = 0; s < NSPLIT; s++) {
    ms[s] = pm[((size_t)h * NSPLIT + s) * S + tb];
    M = fmaxf(M, ms[s]);
  }
  float L = 0.f, acc = 0.f;
  #pragma unroll
  for (int s = 0; s < NSPLIT; s++) {
    float wgt = exp2f(ms[s] - M) * pl[((size_t)h * NSPLIT + s) * S + tb];
    L += wgt;
    acc += wgt * bf2f(po[(((size_t)h * NSPLIT + s) * S + tb) * HDIM + d]);
  }
  attn_out[(size_t)tb * MODEL_DIM + h * HDIM + d] = f2bf(acc / L);
}

extern "C" void kernel_launch(void* const* d_in, const int* in_sizes, int n_in,
                              void* d_out, int out_size, void* d_ws, size_t ws_size,
                              hipStream_t stream) {
  (void)n_in; (void)out_size; (void)ws_size;
  const float* x  = (const float*)d_in[0];
  const float* wq = (const float*)d_in[1];
  const float* bq = (const float*)d_in[2];
  const float* wk = (const float*)d_in[3];
  const float* bk = (const float*)d_in[4];
  const float* wv = (const float*)d_in[5];
  const float* bv = (const float*)d_in[6];
  const float* wo = (const float*)d_in[7];
  const float* bo = (const float*)d_in[8];
  const float* gq = (const float*)d_in[9];
  const float* gk = (const float*)d_in[10];
  const float* freqs = (const float*)d_in[11];
  const float* k_cache = (const float*)d_in[12];
  const float* v_cache = (const float*)d_in[13];
  const int* gs  = (const int*)d_in[14];
  const int* csp = (const int*)d_in[15];

  const int S = in_sizes[0] / MODEL_DIM;
  const int CACHE = in_sizes[12] / (NHEADS * HDIM);
  const int KVcap = (CACHE < MAX_ATTN_W) ? CACHE : MAX_ATTN_W;
  const int Mpad = (S + 127) & ~127;
  const int NQB = Mpad / 128;

  char* ws = (char*)d_ws;
  size_t off = 0;
  auto alloc = [&](size_t bytes) {
    char* p = ws + off;
    off += (bytes + 255) & ~(size_t)255;
    return p;
  };
  u16* xb   = (u16*)alloc((size_t)Mpad * MODEL_DIM * 2);
  u16* wqb  = (u16*)alloc((size_t)MODEL_DIM * MODEL_DIM * 2);
  u16* wkb  = (u16*)alloc((size_t)MODEL_DIM * MODEL_DIM * 2);
  u16* wvb  = (u16*)alloc((size_t)MODEL_DIM * MODEL_DIM * 2);
  u16* wob  = (u16*)alloc((size_t)MODEL_DIM * MODEL_DIM * 2);
  float* q_pre = (float*)alloc((size_t)S * MODEL_DIM * 4);
  float* k_pre = (float*)alloc((size_t)S * MODEL_DIM * 4);
  float* v_pre = (float*)alloc((size_t)S * MODEL_DIM * 4);
  u16* rqb   = (u16*)alloc((size_t)NHEADS * S * HDIM * 2);
  u16* K_all = (u16*)alloc((size_t)NHEADS * KVcap * HDIM * 2);
  u16* VT    = (u16*)alloc((size_t)NHEADS * HDIM * KVcap * 2);
  u16* attn_o = (u16*)alloc((size_t)Mpad * MODEL_DIM * 2);
  u16* po    = (u16*)alloc((size_t)NHEADS * NSPLIT * S * HDIM * 2);
  float* pm  = (float*)alloc((size_t)NHEADS * NSPLIT * S * 4);
  float* pl  = (float*)alloc((size_t)NHEADS * NSPLIT * S * 4);

  const int nx4 = S * MODEL_DIM / 4;
  const int nw4 = MODEL_DIM * MODEL_DIM / 4;
  const int njb = (KVcap + 63) / 64;
  int gx = njb * NHEADS;
  if (gx < (nw4 + 255) / 256) gx = (nw4 + 255) / 256;
  if (gx < (nx4 + 255) / 256) gx = (nx4 + 255) / 256;

  // one fused prep launch: converts + K window + V^T window
  hipLaunchKernelGGL(k_prep, dim3(gx, 7), dim3(256), 0, stream,
                     x, nx4, wq, wk, wv, wo, nw4, xb, wqb, wkb, wvb, wob,
                     k_cache, v_cache, K_all, VT, csp, S, KVcap);

  hipLaunchKernelGGL(k_gemm_qkv128, dim3(Mpad / 128, 3 * MODEL_DIM / 128), dim3(256), 0, stream,
                     xb, wqb, wkb, wvb, bq, bk, bv, q_pre, k_pre, v_pre, S, MODEL_DIM, MODEL_DIM);

  hipLaunchKernelGGL(k_norm_rope, dim3(S), dim3(256), 0, stream,
                     q_pre, k_pre, v_pre, gq, gk, freqs, gs, csp, S, KVcap, rqb, K_all, VT);

  // flat grid: NQB * NHEADS * NSPLIT; (NHEADS*NSPLIT)%8==0 -> bijective XCD grouping
  hipLaunchKernelGGL(k_attn_split, dim3(NQB * NHEADS * NSPLIT), dim3(256), 0, stream,
                     rqb, K_all, VT, po, pm, pl, csp, S, KVcap, NQB);

  hipLaunchKernelGGL(k_attn_reduce, dim3((S + 1) / 2, NHEADS), dim3(256), 0, stream,
                     po, pm, pl, attn_o, S);

  hipLaunchKernelGGL(k_gemm_o128, dim3(Mpad / 128, MODEL_DIM / 128), dim3(256), 0, stream,
                     attn_o, wob, bo, (float*)d_out, S, MODEL_DIM, MODEL_DIM);
}